// Round 2
// baseline (3807.088 us; speedup 1.0000x reference)
//
#include <hip/hip_runtime.h>

typedef unsigned short ushort_t;
typedef unsigned int uint_t;
typedef short v8s __attribute__((ext_vector_type(8)));
typedef float v4f __attribute__((ext_vector_type(4)));

__device__ __forceinline__ float b2f(ushort_t u) {
    uint_t x = ((uint_t)u) << 16;
    float f;
    __builtin_memcpy(&f, &x, 4);
    return f;
}
__device__ __forceinline__ ushort_t f2b(float f) {
    uint_t x;
    __builtin_memcpy(&x, &f, 4);
    uint_t r = (x + 0x7FFFu + ((x >> 16) & 1u)) >> 16;
    return (ushort_t)r;
}

// ---------------------------------------------------------------------------
// K0: fp32 -> bf16 weight conversion into workspace.
// ---------------------------------------------------------------------------
__global__ void k_cvt(const float* __restrict__ src, ushort_t* __restrict__ dst, int n) {
    int i = blockIdx.x * 256 + threadIdx.x;
    if (i < n) dst[i] = f2b(src[i]);
}

// ---------------------------------------------------------------------------
// K1: per-(b,c) scan over t: values(f32), masks/deltas/gamma_x (bf16).
// All activation arrays are [T,B,C].
// ---------------------------------------------------------------------------
__global__ void k_pre(const float* __restrict__ data,
                      const float* __restrict__ Wgx,
                      const float* __restrict__ bgx,
                      float* __restrict__ values, ushort_t* __restrict__ masks,
                      ushort_t* __restrict__ deltas, ushort_t* __restrict__ gammax) {
    int id = blockIdx.x * 256 + threadIdx.x;   // 0..16383 = b*64+c
    int b = id >> 6, c = id & 63;
    float wd = Wgx[c * 64 + c];
    float bg = bgx[c];
    float d_prev = 0.f, m_prev = 0.f;
    for (int t = 0; t < 256; ++t) {
        float x = data[b * 16384 + t * 64 + c];
        bool nan = (x != x);
        float m = nan ? 0.f : 1.f;
        float v = nan ? 0.f : x;
        float d;
        if (t == 0) d = 0.f;
        else if (t == 1) d = 1.f;
        else d = (m_prev == 1.f) ? 1.f : d_prev + 1.f;
        float s = d * wd + bg;
        float gx = (s > 0.f) ? __expf(-s) : 1.f;
        int o = t * 16384 + id;
        values[o] = v;
        masks[o]  = f2b(m);     // 0/1 exact
        deltas[o] = f2b(d);     // integers <=255 exact in bf16
        gammax[o] = f2b(gx);
        m_prev = m; d_prev = d;
    }
}

// ---------------------------------------------------------------------------
// K2: alpha[t,b,i] = sum_j gx[j]*Wc[i,j] + m[j]*Wc[i,64+j] + bc[i]   (bf16 out)
// ---------------------------------------------------------------------------
__global__ void k_alpha(const ushort_t* __restrict__ gammax,
                        const ushort_t* __restrict__ masks,
                        const float* __restrict__ Wcomb,
                        const float* __restrict__ bcomb,
                        ushort_t* __restrict__ alpha) {
    int id = blockIdx.x * 256 + threadIdx.x;   // (t*256+b)*64 + i
    int i = id & 63;
    int tb = id >> 6;
    const ushort_t* gx = gammax + tb * 64;
    const ushort_t* mk = masks + tb * 64;
    const float* w0 = Wcomb + i * 128;
    float acc = bcomb[i];
#pragma unroll
    for (int j0 = 0; j0 < 64; j0 += 8) {
        v8s g = *(const v8s*)(gx + j0);
        v8s m = *(const v8s*)(mk + j0);
#pragma unroll
        for (int j = 0; j < 8; ++j) {
            acc += b2f((ushort_t)g[j]) * w0[j0 + j];
            acc += b2f((ushort_t)m[j]) * w0[64 + j0 + j];
        }
    }
    alpha[id] = f2b(acc);
}

// ---------------------------------------------------------------------------
// Step kernel: grid 256 wgs = (rb: 16 batch-row blocks of 16) x (cb: 16 h-col
// blocks of 32).  Reads h from hcur (written at step t-1), writes hnxt —
// ping-pong removes the intra-launch write/read race.
// ---------------------------------------------------------------------------
__global__ __launch_bounds__(256) void k_step(
    int t,
    const float* __restrict__ values, const ushort_t* __restrict__ masks,
    const ushort_t* __restrict__ deltas, const ushort_t* __restrict__ alpha,
    const ushort_t* __restrict__ Wih, const ushort_t* __restrict__ Whh,
    const float* __restrict__ bih, const float* __restrict__ bhh,
    const ushort_t* __restrict__ Wgh, const float* __restrict__ bgh,
    const ushort_t* __restrict__ Whist, const float* __restrict__ bhist,
    const ushort_t* __restrict__ Wfeat, const float* __restrict__ bfeat,
    const ushort_t* __restrict__ hcur, ushort_t* __restrict__ hnxt,
    float* __restrict__ cst, float* __restrict__ out) {
    __shared__ __attribute__((aligned(16))) ushort_t hlds[16 * 520];   // h_dec bf16
    __shared__ __attribute__((aligned(16))) ushort_t inplds[16 * 136]; // [c_c | m] bf16
    __shared__ __attribute__((aligned(16))) ushort_t xclds[16 * 72];   // x_c bf16
    __shared__ __attribute__((aligned(16))) float d1lds[16 * 64];      // delta_{t+1}
    __shared__ __attribute__((aligned(16))) float xh_lds[16 * 68];
    __shared__ __attribute__((aligned(16))) float zh_lds[16 * 68];
    __shared__ __attribute__((aligned(16))) float gl[4 * 16 * 36];     // gate planes

    int tid = threadIdx.x;
    int w = tid >> 6;            // wave 0..3
    int lane = tid & 63;
    int l15 = lane & 15, quad = lane >> 4;
    int wg = blockIdx.x;
    int rb = wg & 15, cb = wg >> 4;
    int b0 = rb * 16;

    // ---- S0: staging ----
    if (t == 0) {
        v8s z = {0, 0, 0, 0, 0, 0, 0, 0};
        for (int idx = tid; idx < 1040; idx += 256) ((v8s*)hlds)[idx] = z;
    } else {
#pragma unroll
        for (int i = 0; i < 4; ++i) {
            int ch = tid + 256 * i;                 // 1024 chunks of 8 bf16
            int row = ch >> 6, kc = (ch & 63) * 8;
            *(v8s*)(hlds + row * 520 + kc) =
                *(const v8s*)(hcur + (b0 + row) * 512 + kc);
        }
    }
    if (tid < 128) {
        int row = tid >> 3, c8 = (tid & 7) * 8;
        *(v8s*)(inplds + row * 136 + 64 + c8) =
            *(const v8s*)(masks + t * 16384 + (b0 + row) * 64 + c8);
        if (t < 255) {
            v8s d = *(const v8s*)(deltas + (t + 1) * 16384 + (b0 + row) * 64 + c8);
#pragma unroll
            for (int j = 0; j < 8; ++j) d1lds[row * 64 + c8 + j] = b2f((ushort_t)d[j]);
        }
    }
    __syncthreads();

    // ---- S1: x_h = h_dec @ Whist^T  [16 x 64], wave w does cols w*16.. ----
    {
        v4f acc = {0.f, 0.f, 0.f, 0.f};
        int ncol = w * 16 + l15;
        const ushort_t* wrow = Whist + ncol * 512;
#pragma unroll
        for (int kt = 0; kt < 16; ++kt) {
            v8s a = *(const v8s*)(hlds + l15 * 520 + kt * 32 + quad * 8);
            v8s bb = *(const v8s*)(wrow + kt * 32 + quad * 8);
            acc = __builtin_amdgcn_mfma_f32_16x16x32_bf16(a, bb, acc, 0, 0, 0);
        }
#pragma unroll
        for (int r = 0; r < 4; ++r) xh_lds[(quad * 4 + r) * 68 + ncol] = acc[r];
    }
    __syncthreads();

    // ---- S2: elementwise x_c ----
    float xh_r[4], v_r[4], m_r[4], al_r[4];
#pragma unroll
    for (int i = 0; i < 4; ++i) {
        int e = tid + 256 * i;
        int row = e >> 6, col = e & 63;
        int gidx = t * 16384 + (b0 + row) * 64 + col;
        float xh = xh_lds[row * 68 + col] + bhist[col];
        float v = values[gidx];
        float m = b2f(masks[gidx]);
        al_r[i] = b2f(alpha[gidx]);
        float xc = m * v + (1.f - m) * xh;
        xclds[row * 72 + col] = f2b(xc);
        xh_r[i] = xh; v_r[i] = v; m_r[i] = m;
    }
    __syncthreads();

    // ---- S3: z_h = x_c @ (Wfeat off-diag)^T ----
    {
        v4f acc = {0.f, 0.f, 0.f, 0.f};
        int ncol = w * 16 + l15;
        const ushort_t* wrow = Wfeat + ncol * 64;
#pragma unroll
        for (int kt = 0; kt < 2; ++kt) {
            int k0 = kt * 32 + quad * 8;
            v8s a = *(const v8s*)(xclds + l15 * 72 + k0);
            v8s bb = *(const v8s*)(wrow + k0);
#pragma unroll
            for (int j = 0; j < 8; ++j)
                if (k0 + j == ncol) bb[j] = 0;   // zero diagonal
            acc = __builtin_amdgcn_mfma_f32_16x16x32_bf16(a, bb, acc, 0, 0, 0);
        }
#pragma unroll
        for (int r = 0; r < 4; ++r) zh_lds[(quad * 4 + r) * 68 + ncol] = acc[r];
    }
    __syncthreads();

    // ---- S4: elementwise c_h, c_c; write output (cb==0 only) ----
#pragma unroll
    for (int i = 0; i < 4; ++i) {
        int e = tid + 256 * i;
        int row = e >> 6, col = e & 63;
        float zh = zh_lds[row * 68 + col] + bfeat[col];
        float ch = al_r[i] * zh + (1.f - al_r[i]) * xh_r[i];
        float cc = m_r[i] * v_r[i] + (1.f - m_r[i]) * ch;
        inplds[row * 136 + col] = f2b(cc);
        if (cb == 0) out[(b0 + row) * 16384 + t * 64 + col] = cc;
    }
    __syncthreads();

    // ---- S5: gates slice.  wave w = gate w (i,f,g,o); cols cb*32..cb*32+31 ----
#pragma unroll
    for (int nt2 = 0; nt2 < 2; ++nt2) {
        v4f acc = {0.f, 0.f, 0.f, 0.f};
        int hc = cb * 32 + nt2 * 16 + l15;
        int rW = w * 512 + hc;
        const ushort_t* whrow = Whh + rW * 512;
        const ushort_t* wirow = Wih + rW * 128;
#pragma unroll
        for (int kt = 0; kt < 16; ++kt) {
            v8s a = *(const v8s*)(hlds + l15 * 520 + kt * 32 + quad * 8);
            v8s bb = *(const v8s*)(whrow + kt * 32 + quad * 8);
            acc = __builtin_amdgcn_mfma_f32_16x16x32_bf16(a, bb, acc, 0, 0, 0);
        }
#pragma unroll
        for (int kt = 0; kt < 4; ++kt) {
            v8s a = *(const v8s*)(inplds + l15 * 136 + kt * 32 + quad * 8);
            v8s bb = *(const v8s*)(wirow + kt * 32 + quad * 8);
            acc = __builtin_amdgcn_mfma_f32_16x16x32_bf16(a, bb, acc, 0, 0, 0);
        }
        float bias = bih[rW] + bhh[rW];
#pragma unroll
        for (int r = 0; r < 4; ++r)
            gl[w * 576 + (quad * 4 + r) * 36 + nt2 * 16 + l15] = acc[r] + bias;
    }
    __syncthreads();

    // ---- S6: LSTM update + next-step decay ----
#pragma unroll
    for (int i = 0; i < 2; ++i) {
        int e = tid + 256 * i;                  // 0..511
        int hcl = e & 31, row = e >> 5;
        int b = b0 + row;
        int hcg = cb * 32 + hcl;
        float gi = gl[0 * 576 + row * 36 + hcl];
        float gf = gl[1 * 576 + row * 36 + hcl];
        float gg = gl[2 * 576 + row * 36 + hcl];
        float go = gl[3 * 576 + row * 36 + hcl];
        float cold = (t == 0) ? 0.f : cst[b * 512 + hcg];
        float si = 1.f / (1.f + __expf(-gi));
        float sf = 1.f / (1.f + __expf(-gf));
        float tg = 1.f - 2.f / (__expf(2.f * gg) + 1.f);
        float so = 1.f / (1.f + __expf(-go));
        float cn = sf * cold + si * tg;
        cst[b * 512 + hcg] = cn;
        float hn = so * (1.f - 2.f / (__expf(2.f * cn) + 1.f));
        if (t < 255) {
            float s = bgh[hcg];
            const ushort_t* wr = Wgh + hcg * 64;
#pragma unroll
            for (int j0 = 0; j0 < 64; j0 += 8) {
                v8s wv = *(const v8s*)(wr + j0);
#pragma unroll
                for (int j = 0; j < 8; ++j)
                    s += d1lds[row * 64 + j0 + j] * b2f((ushort_t)wv[j]);
            }
            float gam = (s > 0.f) ? __expf(-s) : 1.f;
            hnxt[b * 512 + hcg] = f2b(hn * gam);
        }
    }
}

extern "C" void kernel_launch(void* const* d_in, const int* in_sizes, int n_in,
                              void* d_out, int out_size, void* d_ws, size_t ws_size,
                              hipStream_t stream) {
    const float* data  = (const float*)d_in[0];
    const float* Wih   = (const float*)d_in[1];
    const float* Whh   = (const float*)d_in[2];
    const float* bih   = (const float*)d_in[3];
    const float* bhh   = (const float*)d_in[4];
    const float* Wgh   = (const float*)d_in[5];
    const float* bgh   = (const float*)d_in[6];
    const float* Wgx   = (const float*)d_in[7];
    const float* bgx   = (const float*)d_in[8];
    const float* Whist = (const float*)d_in[9];
    const float* bhist = (const float*)d_in[10];
    const float* Wfeat = (const float*)d_in[11];
    const float* bfeat = (const float*)d_in[12];
    const float* Wcomb = (const float*)d_in[13];
    const float* bcomb = (const float*)d_in[14];
    float* out = (float*)d_out;

    char* ws = (char*)d_ws;
    const size_t NTBC = 256UL * 256 * 64;          // 4,194,304
    float*    values = (float*)ws;    ws += NTBC * 4;
    ushort_t* masks  = (ushort_t*)ws; ws += NTBC * 2;
    ushort_t* deltas = (ushort_t*)ws; ws += NTBC * 2;
    ushort_t* gammax = (ushort_t*)ws; ws += NTBC * 2;
    ushort_t* alphap = (ushort_t*)ws; ws += NTBC * 2;
    ushort_t* Wih_b  = (ushort_t*)ws; ws += 2048UL * 128 * 2;
    ushort_t* Whh_b  = (ushort_t*)ws; ws += 2048UL * 512 * 2;
    ushort_t* Wgh_b  = (ushort_t*)ws; ws += 512UL * 64 * 2;
    ushort_t* Whist_b = (ushort_t*)ws; ws += 64UL * 512 * 2;
    ushort_t* Wfeat_b = (ushort_t*)ws; ws += 64UL * 64 * 2;
    ushort_t* hA     = (ushort_t*)ws; ws += 256UL * 512 * 2;
    ushort_t* hB     = (ushort_t*)ws; ws += 256UL * 512 * 2;
    float*    cst    = (float*)ws;    ws += 256UL * 512 * 4;
    // total ~52 MB of d_ws

    k_cvt<<<1024, 256, 0, stream>>>(Wih, Wih_b, 2048 * 128);
    k_cvt<<<4096, 256, 0, stream>>>(Whh, Whh_b, 2048 * 512);
    k_cvt<<<128, 256, 0, stream>>>(Wgh, Wgh_b, 512 * 64);
    k_cvt<<<128, 256, 0, stream>>>(Whist, Whist_b, 64 * 512);
    k_cvt<<<16, 256, 0, stream>>>(Wfeat, Wfeat_b, 64 * 64);
    k_pre<<<64, 256, 0, stream>>>(data, Wgx, bgx, values, masks, deltas, gammax);
    k_alpha<<<16384, 256, 0, stream>>>(gammax, masks, Wcomb, bcomb, alphap);

    ushort_t* bufs[2] = {hA, hB};
    for (int t = 0; t < 256; ++t) {
        k_step<<<256, 256, 0, stream>>>(t, values, masks, deltas, alphap,
                                        Wih_b, Whh_b, bih, bhh,
                                        Wgh_b, bgh, Whist_b, bhist,
                                        Wfeat_b, bfeat,
                                        bufs[t & 1], bufs[(t + 1) & 1],
                                        cst, out);
    }
}